// Round 4
// baseline (444.378 us; speedup 1.0000x reference)
//
#include <hip/hip_runtime.h>

#define NXROWS 32768
#define NY     4096
#define MCOLS  16
#define JSPLIT 8
#define JCHUNK (NY / JSPLIT)   // 512
#define BLOCK  256

// tps(r) = r^2 * ln(max(r,1e-7)) ; with sq = r^2:
//   = 0.5*ln(2) * max(sq,1e-14) * log2(max(sq,1e-14))
__global__ __launch_bounds__(BLOCK, 4) void rbf_tps_kernel(
    const float* __restrict__ x, const float* __restrict__ y,
    const float* __restrict__ shift, const float* __restrict__ scale,
    const float* __restrict__ coeffs, const int* __restrict__ powers,
    int nR, float* __restrict__ out)
{
    __shared__ float y_s[JCHUNK * 3];       // 6 KB
    __shared__ float c_s[JCHUNK * MCOLS];   // 32 KB

    const int tid   = threadIdx.x;
    const int jbase = blockIdx.y * JCHUNK;

    // stage y chunk (1536 floats, coalesced)
    for (int k = tid; k < JCHUNK * 3; k += BLOCK)
        y_s[k] = y[jbase * 3 + k];
    // stage coeffs chunk (8192 floats as float4, coalesced)
    const float4* cg  = reinterpret_cast<const float4*>(coeffs + (size_t)jbase * MCOLS);
    float4*       cs4 = reinterpret_cast<float4*>(c_s);
    for (int k = tid; k < JCHUNK * MCOLS / 4; k += BLOCK)
        cs4[k] = cg[k];
    __syncthreads();

    const int row = blockIdx.x * BLOCK + tid;
    const float x0 = x[row * 3 + 0];
    const float x1 = x[row * 3 + 1];
    const float x2 = x[row * 3 + 2];

    float acc[MCOLS];
    #pragma unroll
    for (int m = 0; m < MCOLS; ++m) acc[m] = 0.0f;

    #pragma unroll 8
    for (int j = 0; j < JCHUNK; ++j) {
        float dx = x0 - y_s[j * 3 + 0];
        float dy = x1 - y_s[j * 3 + 1];
        float dz = x2 - y_s[j * 3 + 2];
        float sq = dx * dx + dy * dy + dz * dz;
        sq = fmaxf(sq, 1e-14f);
        float t = 0.34657359027997264f * sq * __log2f(sq);  // r^2 ln r

        const float4* c = reinterpret_cast<const float4*>(&c_s[j * MCOLS]);
        #pragma unroll
        for (int q = 0; q < 4; ++q) {
            float4 cv = c[q];
            acc[q * 4 + 0] += t * cv.x;
            acc[q * 4 + 1] += t * cv.y;
            acc[q * 4 + 2] += t * cv.z;
            acc[q * 4 + 3] += t * cv.w;
        }
    }

    // polynomial tail, added exactly once (by the blockIdx.y==0 blocks)
    if (blockIdx.y == 0) {
        const float xin[3] = {x0, x1, x2};
        float xh[3];
        #pragma unroll
        for (int d = 0; d < 3; ++d)
            xh[d] = (xin[d] - shift[d]) / scale[d];
        for (int r = 0; r < nR; ++r) {
            float p = 1.0f;
            for (int d = 0; d < 3; ++d) {
                int pw = powers[r * 3 + d];
                for (int k = 0; k < pw; ++k) p *= xh[d];
            }
            const float* crow = coeffs + (size_t)(NY + r) * MCOLS;
            #pragma unroll
            for (int m = 0; m < MCOLS; ++m) acc[m] += p * crow[m];
        }
    }

    #pragma unroll
    for (int m = 0; m < MCOLS; ++m)
        atomicAdd(&out[(size_t)row * MCOLS + m], acc[m]);
}

extern "C" void kernel_launch(void* const* d_in, const int* in_sizes, int n_in,
                              void* d_out, int out_size, void* d_ws, size_t ws_size,
                              hipStream_t stream) {
    const float* x      = (const float*)d_in[0];
    const float* y      = (const float*)d_in[1];
    const float* shift  = (const float*)d_in[2];
    const float* scale  = (const float*)d_in[3];
    const float* coeffs = (const float*)d_in[4];
    const int*   powers = (const int*)d_in[5];
    const int    nR     = in_sizes[5] / 3;   // 4 monomials for degree 1, ndim 3
    float* out = (float*)d_out;

    // d_out is poisoned 0xAA before every timed call; zero it for the atomics.
    hipMemsetAsync(d_out, 0, (size_t)out_size * sizeof(float), stream);

    dim3 grid(NXROWS / BLOCK, JSPLIT);
    rbf_tps_kernel<<<grid, BLOCK, 0, stream>>>(x, y, shift, scale, coeffs,
                                               powers, nR, out);
}

// Round 5
// 171.847 us; speedup vs baseline: 2.5859x; 2.5859x over previous
//
#include <hip/hip_runtime.h>

#define NXROWS 32768
#define NY     4096
#define MCOLS  16
#define BLOCK  256
#define RPT    4
#define ROWS_PER_BLOCK (BLOCK * RPT)          // 1024
#define GRIDX  (NXROWS / ROWS_PER_BLOCK)      // 32
#define JSPLIT_WS 32
#define JSPLIT_AT 8

#define TPS_C 0.34657359027997264f  // 0.5*ln(2):  r^2 ln r = TPS_C * sq * log2(sq)

// Main pairwise kernel. Each thread owns RPT rows (stride BLOCK), each block
// owns a JCHUNK slice of y/coeffs. Coeffs are read from GLOBAL with a
// wave-uniform address (j-indexed only) -> scalar s_load into SGPRs expected;
// y staged in LDS (broadcast b32 reads, amortized over RPT rows).
template<int JCHUNK, bool USE_WS>
__global__ __launch_bounds__(BLOCK, 4) void rbf_main(
    const float* __restrict__ x, const float* __restrict__ y,
    const float* __restrict__ coeffs, float* __restrict__ dst)
{
    __shared__ float ys[JCHUNK * 3];
    const int tid   = threadIdx.x;
    const int jbase = blockIdx.y * JCHUNK;
    for (int k = tid; k < JCHUNK * 3; k += BLOCK) ys[k] = y[jbase * 3 + k];
    __syncthreads();

    const int rbase = blockIdx.x * ROWS_PER_BLOCK + tid;
    float xv0[RPT], xv1[RPT], xv2[RPT];
    #pragma unroll
    for (int q = 0; q < RPT; ++q) {
        const int row = rbase + q * BLOCK;
        xv0[q] = x[row * 3 + 0];
        xv1[q] = x[row * 3 + 1];
        xv2[q] = x[row * 3 + 2];
    }

    float acc[RPT][MCOLS];
    #pragma unroll
    for (int q = 0; q < RPT; ++q)
        #pragma unroll
        for (int m = 0; m < MCOLS; ++m) acc[q][m] = 0.0f;

    const float4* __restrict__ c4 =
        reinterpret_cast<const float4*>(coeffs) + (size_t)jbase * 4;

    for (int j = 0; j < JCHUNK; ++j) {
        const float y0 = ys[j * 3 + 0];
        const float y1 = ys[j * 3 + 1];
        const float y2 = ys[j * 3 + 2];
        float t[RPT];
        #pragma unroll
        for (int q = 0; q < RPT; ++q) {
            float dx = xv0[q] - y0, dy = xv1[q] - y1, dz = xv2[q] - y2;
            float sq = fmaxf(dx * dx + dy * dy + dz * dz, 1e-14f);
            t[q] = TPS_C * sq * __log2f(sq);
        }
        // wave-uniform global reads -> expect s_load_dwordx16
        const float4 c0 = c4[j * 4 + 0];
        const float4 c1 = c4[j * 4 + 1];
        const float4 c2 = c4[j * 4 + 2];
        const float4 c3 = c4[j * 4 + 3];
        #pragma unroll
        for (int q = 0; q < RPT; ++q) {
            acc[q][0]  += t[q] * c0.x;  acc[q][1]  += t[q] * c0.y;
            acc[q][2]  += t[q] * c0.z;  acc[q][3]  += t[q] * c0.w;
            acc[q][4]  += t[q] * c1.x;  acc[q][5]  += t[q] * c1.y;
            acc[q][6]  += t[q] * c1.z;  acc[q][7]  += t[q] * c1.w;
            acc[q][8]  += t[q] * c2.x;  acc[q][9]  += t[q] * c2.y;
            acc[q][10] += t[q] * c2.z;  acc[q][11] += t[q] * c2.w;
            acc[q][12] += t[q] * c3.x;  acc[q][13] += t[q] * c3.y;
            acc[q][14] += t[q] * c3.z;  acc[q][15] += t[q] * c3.w;
        }
    }

    if (USE_WS) {
        float* plane = dst + (size_t)blockIdx.y * NXROWS * MCOLS;
        #pragma unroll
        for (int q = 0; q < RPT; ++q) {
            const int row = rbase + q * BLOCK;
            float4* o = reinterpret_cast<float4*>(plane + (size_t)row * MCOLS);
            o[0] = make_float4(acc[q][0],  acc[q][1],  acc[q][2],  acc[q][3]);
            o[1] = make_float4(acc[q][4],  acc[q][5],  acc[q][6],  acc[q][7]);
            o[2] = make_float4(acc[q][8],  acc[q][9],  acc[q][10], acc[q][11]);
            o[3] = make_float4(acc[q][12], acc[q][13], acc[q][14], acc[q][15]);
        }
    } else {
        #pragma unroll
        for (int q = 0; q < RPT; ++q) {
            const int row = rbase + q * BLOCK;
            #pragma unroll
            for (int m = 0; m < MCOLS; ++m)
                atomicAdd(&dst[(size_t)row * MCOLS + m], acc[q][m]);
        }
    }
}

// Reduce over JSPLIT_WS partial planes + apply polynomial tail. One thread
// per (row, m-quad): 32768*4 threads.
__global__ __launch_bounds__(BLOCK) void rbf_reduce(
    const float* __restrict__ ws, const float* __restrict__ x,
    const float* __restrict__ shift, const float* __restrict__ scale,
    const float* __restrict__ coeffs, const int* __restrict__ powers,
    int nR, float* __restrict__ out)
{
    const int idx = blockIdx.x * BLOCK + threadIdx.x;
    const int row = idx >> 2, mq = idx & 3;
    float4 s = make_float4(0.f, 0.f, 0.f, 0.f);
    #pragma unroll
    for (int sp = 0; sp < JSPLIT_WS; ++sp) {
        const float4 v = *reinterpret_cast<const float4*>(
            ws + (size_t)sp * NXROWS * MCOLS + (size_t)row * MCOLS + mq * 4);
        s.x += v.x; s.y += v.y; s.z += v.z; s.w += v.w;
    }
    float xh[3];
    #pragma unroll
    for (int d = 0; d < 3; ++d) xh[d] = (x[row * 3 + d] - shift[d]) / scale[d];
    for (int r = 0; r < nR; ++r) {
        float p = 1.0f;
        for (int d = 0; d < 3; ++d) {
            int pw = powers[r * 3 + d];
            for (int k = 0; k < pw; ++k) p *= xh[d];
        }
        const float4 cv = *reinterpret_cast<const float4*>(
            coeffs + (size_t)(NY + r) * MCOLS + mq * 4);
        s.x += p * cv.x; s.y += p * cv.y; s.z += p * cv.z; s.w += p * cv.w;
    }
    *reinterpret_cast<float4*>(out + (size_t)row * MCOLS + mq * 4) = s;
}

// Fallback (ws too small): polynomial tail via atomics on top of rbf_main<.,false>.
__global__ __launch_bounds__(BLOCK) void rbf_poly_atomic(
    const float* __restrict__ x, const float* __restrict__ shift,
    const float* __restrict__ scale, const float* __restrict__ coeffs,
    const int* __restrict__ powers, int nR, float* __restrict__ out)
{
    const int idx = blockIdx.x * BLOCK + threadIdx.x;
    const int row = idx >> 2, mq = idx & 3;
    float xh[3];
    #pragma unroll
    for (int d = 0; d < 3; ++d) xh[d] = (x[row * 3 + d] - shift[d]) / scale[d];
    float4 s = make_float4(0.f, 0.f, 0.f, 0.f);
    for (int r = 0; r < nR; ++r) {
        float p = 1.0f;
        for (int d = 0; d < 3; ++d) {
            int pw = powers[r * 3 + d];
            for (int k = 0; k < pw; ++k) p *= xh[d];
        }
        const float4 cv = *reinterpret_cast<const float4*>(
            coeffs + (size_t)(NY + r) * MCOLS + mq * 4);
        s.x += p * cv.x; s.y += p * cv.y; s.z += p * cv.z; s.w += p * cv.w;
    }
    float* o = out + (size_t)row * MCOLS + mq * 4;
    atomicAdd(o + 0, s.x); atomicAdd(o + 1, s.y);
    atomicAdd(o + 2, s.z); atomicAdd(o + 3, s.w);
}

extern "C" void kernel_launch(void* const* d_in, const int* in_sizes, int n_in,
                              void* d_out, int out_size, void* d_ws, size_t ws_size,
                              hipStream_t stream) {
    const float* x      = (const float*)d_in[0];
    const float* y      = (const float*)d_in[1];
    const float* shift  = (const float*)d_in[2];
    const float* scale  = (const float*)d_in[3];
    const float* coeffs = (const float*)d_in[4];
    const int*   powers = (const int*)d_in[5];
    const int    nR     = in_sizes[5] / 3;
    float* out = (float*)d_out;

    const size_t ws_needed = (size_t)JSPLIT_WS * NXROWS * MCOLS * sizeof(float); // 64 MiB
    if (ws_size >= ws_needed) {
        float* ws = (float*)d_ws;
        rbf_main<NY / JSPLIT_WS, true>
            <<<dim3(GRIDX, JSPLIT_WS), BLOCK, 0, stream>>>(x, y, coeffs, ws);
        rbf_reduce<<<NXROWS * 4 / BLOCK, BLOCK, 0, stream>>>(
            ws, x, shift, scale, coeffs, powers, nR, out);
    } else {
        hipMemsetAsync(d_out, 0, (size_t)out_size * sizeof(float), stream);
        rbf_main<NY / JSPLIT_AT, false>
            <<<dim3(GRIDX, JSPLIT_AT), BLOCK, 0, stream>>>(x, y, coeffs, out);
        rbf_poly_atomic<<<NXROWS * 4 / BLOCK, BLOCK, 0, stream>>>(
            x, shift, scale, coeffs, powers, nR, out);
    }
}

// Round 6
// 155.915 us; speedup vs baseline: 2.8501x; 1.1022x over previous
//
#include <hip/hip_runtime.h>

#define NXROWS 32768
#define NY     4096
#define MCOLS  16
#define BLOCK  256
#define KSPLIT 4
#define KCHUNK (NY / KSPLIT)                 // 1024
#define ROWS_PER_BLOCK 64                    // 4 waves x 16 rows
#define GRIDX  (NXROWS / ROWS_PER_BLOCK)     // 512

#define TPS_C 0.34657359027997264f  // 0.5*ln2: r^2 ln r = TPS_C * sq * log2(sq)

typedef __bf16 bf16x8 __attribute__((ext_vector_type(8)));
typedef short  s16x8  __attribute__((ext_vector_type(8)));
typedef float  f32x4  __attribute__((ext_vector_type(4)));

// ws layout (bytes):
//   [0,      65536)   y4   : 4096 x float4 (xyz + pad)
//   [65536, 196608)   cT   : bf16 [16][4096]  (coeffs transposed)
//   [262144, +8MiB)   part : f32 [KSPLIT][NXROWS][MCOLS]
#define WS_Y4_OFF   0
#define WS_CT_OFF   65536
#define WS_PART_OFF 262144
#define WS_NEEDED   (WS_PART_OFF + (size_t)KSPLIT * NXROWS * MCOLS * 4)

static __device__ __forceinline__ unsigned short f2bfu(float f) {
    __bf16 h = (__bf16)f;
    return __builtin_bit_cast(unsigned short, h);
}

// ---- prep: y -> float4-padded; coeffs[0:NY][16] -> bf16 transposed [16][NY]
__global__ __launch_bounds__(BLOCK) void rbf_prep(
    const float* __restrict__ y, const float* __restrict__ coeffs,
    float4* __restrict__ y4, unsigned short* __restrict__ cT)
{
    const int j = blockIdx.x * BLOCK + threadIdx.x;   // 0..NY-1
    y4[j] = make_float4(y[3 * j], y[3 * j + 1], y[3 * j + 2], 0.0f);
    const float4* c4 = reinterpret_cast<const float4*>(coeffs + (size_t)j * MCOLS);
    #pragma unroll
    for (int g = 0; g < 4; ++g) {
        const float4 v = c4[g];
        cT[(size_t)(g * 4 + 0) * NY + j] = f2bfu(v.x);
        cT[(size_t)(g * 4 + 1) * NY + j] = f2bfu(v.y);
        cT[(size_t)(g * 4 + 2) * NY + j] = f2bfu(v.z);
        cT[(size_t)(g * 4 + 3) * NY + j] = f2bfu(v.w);
    }
}

// ---- main: per wave one 16-row M-tile; K swept in 32-steps via MFMA.
// A-frag: lane l -> row = l&15, k = (l>>4)*8 + e (e = 0..7)
// B-frag: lane l -> n   = l&15, k = (l>>4)*8 + e   (cT rows are contiguous k)
// C:      lane l -> col = l&15, row = (l>>4)*4 + reg
__global__ __launch_bounds__(BLOCK, 4) void rbf_mfma(
    const float* __restrict__ x, const float4* __restrict__ y4,
    const unsigned short* __restrict__ cT, float* __restrict__ part)
{
    const int lane = threadIdx.x & 63;
    const int wid  = threadIdx.x >> 6;
    const int n    = lane & 15;
    const int q    = lane >> 4;
    const int rowA = blockIdx.x * ROWS_PER_BLOCK + wid * 16 + n;
    const float x0 = x[rowA * 3 + 0];
    const float x1 = x[rowA * 3 + 1];
    const float x2 = x[rowA * 3 + 2];
    const int kbase = blockIdx.y * KCHUNK;

    f32x4 acc = {0.f, 0.f, 0.f, 0.f};
    for (int ks = 0; ks < KCHUNK / 32; ++ks) {
        const int k0 = kbase + ks * 32 + q * 8;
        bf16x8 af;
        #pragma unroll
        for (int e = 0; e < 8; ++e) {
            const float4 yv = y4[k0 + e];
            const float dx = x0 - yv.x, dy = x1 - yv.y, dz = x2 - yv.z;
            const float sq = fmaxf(fmaf(dx, dx, fmaf(dy, dy, dz * dz)), 1e-14f);
            af[e] = (__bf16)(TPS_C * sq * __log2f(sq));
        }
        const s16x8 braw = *reinterpret_cast<const s16x8*>(cT + (size_t)n * NY + k0);
        acc = __builtin_amdgcn_mfma_f32_16x16x32_bf16(
            af, __builtin_bit_cast(bf16x8, braw), acc, 0, 0, 0);
    }

    float* dst = part + ((size_t)blockIdx.y * NXROWS +
                         blockIdx.x * ROWS_PER_BLOCK + wid * 16 + q * 4) * MCOLS + n;
    #pragma unroll
    for (int r = 0; r < 4; ++r) dst[(size_t)r * MCOLS] = acc[r];
}

// ---- reduce KSPLIT partial planes + polynomial tail; full overwrite of out.
__global__ __launch_bounds__(BLOCK) void rbf_reduce(
    const float* __restrict__ part, const float* __restrict__ x,
    const float* __restrict__ shift, const float* __restrict__ scale,
    const float* __restrict__ coeffs, const int* __restrict__ powers,
    int nR, float* __restrict__ out)
{
    const int idx = blockIdx.x * BLOCK + threadIdx.x;
    const int row = idx >> 2, mq = idx & 3;
    f32x4 s = {0.f, 0.f, 0.f, 0.f};
    #pragma unroll
    for (int sp = 0; sp < KSPLIT; ++sp) {
        const f32x4 v = *reinterpret_cast<const f32x4*>(
            part + (size_t)sp * NXROWS * MCOLS + (size_t)row * MCOLS + mq * 4);
        s += v;
    }
    float xh[3];
    #pragma unroll
    for (int d = 0; d < 3; ++d) xh[d] = (x[row * 3 + d] - shift[d]) / scale[d];
    for (int r = 0; r < nR; ++r) {
        float p = 1.0f;
        for (int d = 0; d < 3; ++d) {
            const int pw = powers[r * 3 + d];
            for (int k = 0; k < pw; ++k) p *= xh[d];
        }
        const f32x4 cv = *reinterpret_cast<const f32x4*>(
            coeffs + (size_t)(NY + r) * MCOLS + mq * 4);
        s += p * cv;
    }
    *reinterpret_cast<f32x4*>(out + (size_t)row * MCOLS + mq * 4) = s;
}

// ---- fallback (ws too small): round-5 f32 atomic path, kept minimal.
__global__ __launch_bounds__(BLOCK) void rbf_f32_atomic(
    const float* __restrict__ x, const float* __restrict__ y,
    const float* __restrict__ coeffs, float* __restrict__ out)
{
    const int tid = threadIdx.x;
    const int jbase = blockIdx.y * 512;
    const int row = blockIdx.x * BLOCK + tid;
    const float x0 = x[row * 3], x1 = x[row * 3 + 1], x2 = x[row * 3 + 2];
    float acc[MCOLS];
    #pragma unroll
    for (int m = 0; m < MCOLS; ++m) acc[m] = 0.f;
    const float4* c4 = reinterpret_cast<const float4*>(coeffs) + (size_t)jbase * 4;
    for (int j = 0; j < 512; ++j) {
        const float dx = x0 - y[(jbase + j) * 3 + 0];
        const float dy = x1 - y[(jbase + j) * 3 + 1];
        const float dz = x2 - y[(jbase + j) * 3 + 2];
        const float sq = fmaxf(dx * dx + dy * dy + dz * dz, 1e-14f);
        const float t = TPS_C * sq * __log2f(sq);
        #pragma unroll
        for (int g = 0; g < 4; ++g) {
            const float4 cv = c4[j * 4 + g];
            acc[g * 4 + 0] += t * cv.x; acc[g * 4 + 1] += t * cv.y;
            acc[g * 4 + 2] += t * cv.z; acc[g * 4 + 3] += t * cv.w;
        }
    }
    #pragma unroll
    for (int m = 0; m < MCOLS; ++m)
        atomicAdd(&out[(size_t)row * MCOLS + m], acc[m]);
}

__global__ __launch_bounds__(BLOCK) void rbf_poly_atomic(
    const float* __restrict__ x, const float* __restrict__ shift,
    const float* __restrict__ scale, const float* __restrict__ coeffs,
    const int* __restrict__ powers, int nR, float* __restrict__ out)
{
    const int idx = blockIdx.x * BLOCK + threadIdx.x;
    const int row = idx >> 2, mq = idx & 3;
    float xh[3];
    #pragma unroll
    for (int d = 0; d < 3; ++d) xh[d] = (x[row * 3 + d] - shift[d]) / scale[d];
    f32x4 s = {0.f, 0.f, 0.f, 0.f};
    for (int r = 0; r < nR; ++r) {
        float p = 1.0f;
        for (int d = 0; d < 3; ++d) {
            const int pw = powers[r * 3 + d];
            for (int k = 0; k < pw; ++k) p *= xh[d];
        }
        const f32x4 cv = *reinterpret_cast<const f32x4*>(
            coeffs + (size_t)(NY + r) * MCOLS + mq * 4);
        s += p * cv;
    }
    float* o = out + (size_t)row * MCOLS + mq * 4;
    atomicAdd(o + 0, s.x); atomicAdd(o + 1, s.y);
    atomicAdd(o + 2, s.z); atomicAdd(o + 3, s.w);
}

extern "C" void kernel_launch(void* const* d_in, const int* in_sizes, int n_in,
                              void* d_out, int out_size, void* d_ws, size_t ws_size,
                              hipStream_t stream) {
    const float* x      = (const float*)d_in[0];
    const float* y      = (const float*)d_in[1];
    const float* shift  = (const float*)d_in[2];
    const float* scale  = (const float*)d_in[3];
    const float* coeffs = (const float*)d_in[4];
    const int*   powers = (const int*)d_in[5];
    const int    nR     = in_sizes[5] / 3;
    float* out = (float*)d_out;

    if (ws_size >= WS_NEEDED) {
        char* ws = (char*)d_ws;
        float4*         y4   = (float4*)(ws + WS_Y4_OFF);
        unsigned short* cT   = (unsigned short*)(ws + WS_CT_OFF);
        float*          part = (float*)(ws + WS_PART_OFF);
        rbf_prep<<<NY / BLOCK, BLOCK, 0, stream>>>(y, coeffs, y4, cT);
        rbf_mfma<<<dim3(GRIDX, KSPLIT), BLOCK, 0, stream>>>(x, y4, cT, part);
        rbf_reduce<<<NXROWS * 4 / BLOCK, BLOCK, 0, stream>>>(
            part, x, shift, scale, coeffs, powers, nR, out);
    } else {
        hipMemsetAsync(d_out, 0, (size_t)out_size * sizeof(float), stream);
        rbf_f32_atomic<<<dim3(NXROWS / BLOCK, NY / 512), BLOCK, 0, stream>>>(
            x, y, coeffs, out);
        rbf_poly_atomic<<<NXROWS * 4 / BLOCK, BLOCK, 0, stream>>>(
            x, shift, scale, coeffs, powers, nR, out);
    }
}

// Round 7
// 114.026 us; speedup vs baseline: 3.8972x; 1.3674x over previous
//
#include <hip/hip_runtime.h>

#define NXROWS 32768
#define NY     4096
#define MCOLS  16
#define BLOCK  256
#define KSPLIT 4
#define KCHUNK (NY / KSPLIT)               // 1024
#define NITER  (KCHUNK / 32)               // 32
#define ROWS_PER_BLOCK 128                 // 4 waves x 32 rows
#define GRIDX  (NXROWS / ROWS_PER_BLOCK)   // 256

#define TPS_C 0.34657359027997264f  // 0.5*ln2: r^2 ln r = TPS_C * sq * log2(sq)

typedef __bf16 bf16x8 __attribute__((ext_vector_type(8)));
typedef short  s16x8  __attribute__((ext_vector_type(8)));
typedef float  f32x4  __attribute__((ext_vector_type(4)));

// ws layout (bytes). Pads absorb the unguarded last-iteration prefetch
// (garbage loaded, never consumed, stays inside ws).
//   [0,     65536)  y4 : 4096 x float4 (y0,y1,y2,|y|^2)   + 1KB pad
//   [66560, 197632) cT : bf16 [16][4096] = TPS_C * coeffs^T + 1KB pad
#define WS_Y4_OFF 0
#define WS_CT_OFF 66560
#define WS_END    (WS_CT_OFF + 131072 + 1024)

static __device__ __forceinline__ unsigned short f2bfu(float f) {
    __bf16 h = (__bf16)f;
    return __builtin_bit_cast(unsigned short, h);
}

// ---- prep: poly tail -> out (full overwrite), cT (TPS_C-scaled bf16
// transposed coeffs), y4. Branch ranges are multiples of BLOCK -> no
// intra-block divergence.
__global__ __launch_bounds__(BLOCK) void rbf_prep2(
    const float* __restrict__ y, const float* __restrict__ coeffs,
    const float* __restrict__ x, const float* __restrict__ shift,
    const float* __restrict__ scale, const int* __restrict__ powers, int nR,
    float4* __restrict__ y4, unsigned int* __restrict__ cTw,
    float* __restrict__ out)
{
    const int idx = blockIdx.x * BLOCK + threadIdx.x;
    if (idx < NXROWS * 4) {                       // poly tail -> out
        const int row = idx >> 2, mq = idx & 3;
        float xh[3];
        #pragma unroll
        for (int d = 0; d < 3; ++d)
            xh[d] = (x[row * 3 + d] - shift[d]) / scale[d];
        f32x4 s = {0.f, 0.f, 0.f, 0.f};
        for (int r = 0; r < nR; ++r) {
            float p = 1.0f;
            for (int d = 0; d < 3; ++d) {
                const int pw = powers[r * 3 + d];
                for (int k = 0; k < pw; ++k) p *= xh[d];
            }
            const f32x4 cv = *reinterpret_cast<const f32x4*>(
                coeffs + (size_t)(NY + r) * MCOLS + mq * 4);
            s += p * cv;
        }
        *reinterpret_cast<f32x4*>(out + (size_t)row * MCOLS + mq * 4) = s;
    } else if (idx < NXROWS * 4 + MCOLS * NY / 2) {   // cT build
        const int t  = idx - NXROWS * 4;
        const int m  = t >> 11;                   // 2048 j-pairs per m
        const int jp = (t & 2047) * 2;
        const unsigned short u0 = f2bfu(TPS_C * coeffs[(size_t)jp * MCOLS + m]);
        const unsigned short u1 = f2bfu(TPS_C * coeffs[(size_t)(jp + 1) * MCOLS + m]);
        cTw[((size_t)m * NY + jp) >> 1] = (unsigned int)u0 | ((unsigned int)u1 << 16);
    } else {                                      // y4 build
        const int j = idx - NXROWS * 4 - MCOLS * NY / 2;  // < NY
        const float y0 = y[3 * j], y1 = y[3 * j + 1], y2 = y[3 * j + 2];
        y4[j] = make_float4(y0, y1, y2, y0 * y0 + y1 * y1 + y2 * y2);
    }
}

// ---- main: per wave 2 M-tiles (32 rows); K in 32-steps via MFMA with
// register double-buffered prefetch of y4 + B-frag.
// A-frag: lane l -> row=l&15, k=(l>>4)*8+e ; B-frag: n=l&15, k=(l>>4)*8+e
// C/D:    lane l -> col=l&15, row=(l>>4)*4+reg   (m89-verified)
__global__ __launch_bounds__(BLOCK, 4) void rbf_mfma2(
    const float* __restrict__ x, const float4* __restrict__ y4,
    const unsigned short* __restrict__ cT, float* __restrict__ out)
{
    const int lane = threadIdx.x & 63;
    const int wid  = threadIdx.x >> 6;
    const int n    = lane & 15;
    const int q    = lane >> 4;
    const int rowBase = blockIdx.x * ROWS_PER_BLOCK + wid * 32;
    const int r0 = rowBase + n;
    const int r1 = rowBase + 16 + n;
    const int kbase = blockIdx.y * KCHUNK;

    const float x00 = x[r0 * 3], x01 = x[r0 * 3 + 1], x02 = x[r0 * 3 + 2];
    const float x10 = x[r1 * 3], x11 = x[r1 * 3 + 1], x12 = x[r1 * 3 + 2];
    const float sx0 = x00 * x00 + x01 * x01 + x02 * x02;
    const float sx1 = x10 * x10 + x11 * x11 + x12 * x12;
    const float a00 = -2.f * x00, a01 = -2.f * x01, a02 = -2.f * x02;
    const float a10 = -2.f * x10, a11 = -2.f * x11, a12 = -2.f * x12;

    const float4* yb = y4 + kbase + q * 8;
    const unsigned short* cb = cT + (size_t)n * NY + kbase + q * 8;

    f32x4 acc0 = {0.f, 0.f, 0.f, 0.f}, acc1 = {0.f, 0.f, 0.f, 0.f};
    float4 yA[8], yB[8];
    s16x8 bA, bB;

#define LOADT(Y, B, K) do {                                              \
    _Pragma("unroll")                                                    \
    for (int e = 0; e < 8; ++e) Y[e] = yb[(K) + e];                      \
    B = *reinterpret_cast<const s16x8*>(cb + (K));                       \
} while (0)

#define CONSUME(Y, B) do {                                               \
    bf16x8 af0, af1;                                                     \
    _Pragma("unroll")                                                    \
    for (int e = 0; e < 8; ++e) {                                        \
        const float4 yv = Y[e];                                          \
        float s0 = fmaf(a00, yv.x, fmaf(a01, yv.y, fmaf(a02, yv.z, sx0 + yv.w))); \
        float s1 = fmaf(a10, yv.x, fmaf(a11, yv.y, fmaf(a12, yv.z, sx1 + yv.w))); \
        s0 = fmaxf(s0, 1e-14f);                                          \
        s1 = fmaxf(s1, 1e-14f);                                          \
        af0[e] = (__bf16)(s0 * __log2f(s0));                             \
        af1[e] = (__bf16)(s1 * __log2f(s1));                             \
    }                                                                    \
    const bf16x8 bf = __builtin_bit_cast(bf16x8, B);                     \
    acc0 = __builtin_amdgcn_mfma_f32_16x16x32_bf16(af0, bf, acc0, 0, 0, 0); \
    acc1 = __builtin_amdgcn_mfma_f32_16x16x32_bf16(af1, bf, acc1, 0, 0, 0); \
} while (0)

    LOADT(yA, bA, 0);
    for (int ks = 0; ks < NITER; ks += 2) {
        LOADT(yB, bB, (ks + 1) * 32);
        CONSUME(yA, bA);
        LOADT(yA, bA, (ks + 2) * 32);   // last prefetch reads ws pad; unused
        CONSUME(yB, bB);
    }
#undef LOADT
#undef CONSUME

    // no-return f32 atomic adds (fire-and-forget) on top of prep's poly init
    float* o0 = out + (size_t)(rowBase + q * 4) * MCOLS + n;
    float* o1 = out + (size_t)(rowBase + 16 + q * 4) * MCOLS + n;
    #pragma unroll
    for (int r = 0; r < 4; ++r) {
        atomicAdd(o0 + (size_t)r * MCOLS, acc0[r]);
        atomicAdd(o1 + (size_t)r * MCOLS, acc1[r]);
    }
}

// ---- fallback (ws too small; effectively never): pure f32 atomic path.
__global__ __launch_bounds__(BLOCK) void rbf_f32_atomic(
    const float* __restrict__ x, const float* __restrict__ y,
    const float* __restrict__ coeffs, float* __restrict__ out)
{
    const int jbase = blockIdx.y * 512;
    const int row = blockIdx.x * BLOCK + threadIdx.x;
    const float x0 = x[row * 3], x1 = x[row * 3 + 1], x2 = x[row * 3 + 2];
    float acc[MCOLS];
    #pragma unroll
    for (int m = 0; m < MCOLS; ++m) acc[m] = 0.f;
    const float4* c4 = reinterpret_cast<const float4*>(coeffs) + (size_t)jbase * 4;
    for (int j = 0; j < 512; ++j) {
        const float dx = x0 - y[(jbase + j) * 3 + 0];
        const float dy = x1 - y[(jbase + j) * 3 + 1];
        const float dz = x2 - y[(jbase + j) * 3 + 2];
        const float sq = fmaxf(dx * dx + dy * dy + dz * dz, 1e-14f);
        const float t = TPS_C * sq * __log2f(sq);
        #pragma unroll
        for (int g = 0; g < 4; ++g) {
            const float4 cv = c4[j * 4 + g];
            acc[g * 4 + 0] += t * cv.x; acc[g * 4 + 1] += t * cv.y;
            acc[g * 4 + 2] += t * cv.z; acc[g * 4 + 3] += t * cv.w;
        }
    }
    #pragma unroll
    for (int m = 0; m < MCOLS; ++m)
        atomicAdd(&out[(size_t)row * MCOLS + m], acc[m]);
}

__global__ __launch_bounds__(BLOCK) void rbf_poly_atomic(
    const float* __restrict__ x, const float* __restrict__ shift,
    const float* __restrict__ scale, const float* __restrict__ coeffs,
    const int* __restrict__ powers, int nR, float* __restrict__ out)
{
    const int idx = blockIdx.x * BLOCK + threadIdx.x;
    const int row = idx >> 2, mq = idx & 3;
    float xh[3];
    #pragma unroll
    for (int d = 0; d < 3; ++d) xh[d] = (x[row * 3 + d] - shift[d]) / scale[d];
    f32x4 s = {0.f, 0.f, 0.f, 0.f};
    for (int r = 0; r < nR; ++r) {
        float p = 1.0f;
        for (int d = 0; d < 3; ++d) {
            const int pw = powers[r * 3 + d];
            for (int k = 0; k < pw; ++k) p *= xh[d];
        }
        const f32x4 cv = *reinterpret_cast<const f32x4*>(
            coeffs + (size_t)(NY + r) * MCOLS + mq * 4);
        s += p * cv;
    }
    float* o = out + (size_t)row * MCOLS + mq * 4;
    atomicAdd(o + 0, s.x); atomicAdd(o + 1, s.y);
    atomicAdd(o + 2, s.z); atomicAdd(o + 3, s.w);
}

extern "C" void kernel_launch(void* const* d_in, const int* in_sizes, int n_in,
                              void* d_out, int out_size, void* d_ws, size_t ws_size,
                              hipStream_t stream) {
    const float* x      = (const float*)d_in[0];
    const float* y      = (const float*)d_in[1];
    const float* shift  = (const float*)d_in[2];
    const float* scale  = (const float*)d_in[3];
    const float* coeffs = (const float*)d_in[4];
    const int*   powers = (const int*)d_in[5];
    const int    nR     = in_sizes[5] / 3;
    float* out = (float*)d_out;

    if (ws_size >= WS_END) {
        char* ws = (char*)d_ws;
        float4*         y4  = (float4*)(ws + WS_Y4_OFF);
        unsigned short* cT  = (unsigned short*)(ws + WS_CT_OFF);
        unsigned int*   cTw = (unsigned int*)(ws + WS_CT_OFF);
        // prep: 131072 poly + 32768 cT + 4096 y4 threads = 656 blocks exactly
        rbf_prep2<<<(NXROWS * 4 + MCOLS * NY / 2 + NY) / BLOCK, BLOCK, 0, stream>>>(
            y, coeffs, x, shift, scale, powers, nR, y4, cTw, out);
        rbf_mfma2<<<dim3(GRIDX, KSPLIT), BLOCK, 0, stream>>>(x, y4, cT, out);
    } else {
        hipMemsetAsync(d_out, 0, (size_t)out_size * sizeof(float), stream);
        rbf_f32_atomic<<<dim3(NXROWS / BLOCK, NY / 512), BLOCK, 0, stream>>>(
            x, y, coeffs, out);
        rbf_poly_atomic<<<NXROWS * 4 / BLOCK, BLOCK, 0, stream>>>(
            x, shift, scale, coeffs, powers, nR, out);
    }
}